// Round 4
// baseline (513.783 us; speedup 1.0000x reference)
//
#include <hip/hip_runtime.h>
#include <hip/hip_bf16.h>
#include <cstdint>

using u16 = unsigned short;
using u32 = unsigned int;

typedef __bf16 bf16x8 __attribute__((ext_vector_type(8)));
typedef float  f32x4  __attribute__((ext_vector_type(4)));

#define DEV static __device__ __forceinline__

DEV float bf2f(u16 u){ union { u32 u; float f; } c; c.u = ((u32)u) << 16; return c.f; }

// hardware RNE f32->bf16 (v_cvt_pk_bf16_f32 on gfx950)
DEV u16 f2bf(float f){
  __bf16 h = (__bf16)f;
  return __builtin_bit_cast(u16, h);
}

DEV float fast_rcp(float x){ return __builtin_amdgcn_rcpf(x); }

DEV void async16(const u16* g, u16* l){
  __builtin_amdgcn_global_load_lds((const __attribute__((address_space(1))) u32*)g,
                                   (__attribute__((address_space(3))) u32*)l,
                                   16, 0, 0);
}

// ---------------- fused weight transposes + f32->bf16 (one launch) ----------------
__global__ __launch_bounds__(256)
void transpose_all(const float* __restrict__ W0, const float* __restrict__ W1,
                   const float* __restrict__ W2, const float* __restrict__ W3,
                   const float* __restrict__ W4, const float* __restrict__ W5,
                   u16* __restrict__ T0, u16* __restrict__ T1, u16* __restrict__ T2,
                   u16* __restrict__ T3, u16* __restrict__ T4, u16* __restrict__ T5){
  const int z = blockIdx.z;
  const float* W; u16* WT; int R, C;
  switch (z){
    case 0:  W = W0; WT = T0; R = 512;  C = 1024; break;
    case 1:  W = W1; WT = T1; R = 512;  C = 1024; break;
    case 2:  W = W2; WT = T2; R = 512;  C = 1024; break;
    case 3:  W = W3; WT = T3; R = 1024; C = 512;  break;
    case 4:  W = W4; WT = T4; R = 512;  C = 1024; break;
    default: W = W5; WT = T5; R = 1024; C = 512;  break;
  }
  const int c0 = blockIdx.x * 32, r0 = blockIdx.y * 32;
  if (c0 >= C || r0 >= R) return;
  __shared__ float tile[32][33];
  const int tx = threadIdx.x, ty = threadIdx.y;  // (32,8)
  #pragma unroll
  for (int j = 0; j < 4; ++j)
    tile[ty + j*8][tx] = W[(size_t)(r0 + ty + j*8) * C + (c0 + tx)];
  __syncthreads();
  #pragma unroll
  for (int j = 0; j < 4; ++j)
    WT[(size_t)(c0 + ty + j*8) * R + (r0 + tx)] = f2bf(tile[tx][ty + j*8]);
}

// ---------------- LayerNorm: one wave per 512-elem row ----------------
template<bool BF16IN>
__global__ __launch_bounds__(256)
void ln_kernel(const void* __restrict__ xin, const float* __restrict__ gamma,
               const float* __restrict__ beta, u16* __restrict__ xout){
  const int wid = threadIdx.x >> 6;
  const int lane = threadIdx.x & 63;
  const size_t row = (size_t)blockIdx.x * 4 + wid;
  const int d0 = lane * 8;
  float v[8];
  if constexpr (BF16IN){
    const u16* xp = (const u16*)xin + row * 512 + d0;
    uint4 p = *(const uint4*)xp;
    const u16* s = (const u16*)&p;
    #pragma unroll
    for (int i = 0; i < 8; ++i) v[i] = bf2f(s[i]);
  } else {
    const float* xp = (const float*)xin + row * 512 + d0;
    float4 p0 = *(const float4*)xp;
    float4 p1 = *(const float4*)(xp + 4);
    v[0]=p0.x; v[1]=p0.y; v[2]=p0.z; v[3]=p0.w;
    v[4]=p1.x; v[5]=p1.y; v[6]=p1.z; v[7]=p1.w;
  }
  float s = 0.f, sq = 0.f;
  #pragma unroll
  for (int i = 0; i < 8; ++i){ s += v[i]; sq += v[i]*v[i]; }
  #pragma unroll
  for (int o = 32; o >= 1; o >>= 1){ s += __shfl_xor(s, o); sq += __shfl_xor(sq, o); }
  const float mu  = s * (1.0f/512.0f);
  const float var = sq * (1.0f/512.0f) - mu*mu;
  const float rstd = rsqrtf(var + 1e-5f);
  u16 o8[8];
  #pragma unroll
  for (int i = 0; i < 8; ++i)
    o8[i] = f2bf((v[i]-mu)*rstd*gamma[d0+i] + beta[d0+i]);
  *(uint4*)(xout + row*512 + d0) = *(const uint4*)o8;
}

// ---- slim AFT: weighted[t,h] = sum_b numer*V / sum_b numer  (Yt folded into GEMM1) ----
__global__ __launch_bounds__(256)
void aft_weighted(const u16* __restrict__ numer, const u16* __restrict__ V,
                  u16* __restrict__ wgt){
  const size_t TH = (size_t)4096 * 1024;
  const size_t i8 = ((size_t)blockIdx.x * 256 + threadIdx.x) * 8;
  float den[8], ws[8];
  #pragma unroll
  for (int j = 0; j < 8; ++j){ den[j] = 0.f; ws[j] = 0.f; }
  #pragma unroll
  for (int b = 0; b < 8; ++b){
    uint4 pn = *(const uint4*)(numer + b*TH + i8);
    uint4 pv = *(const uint4*)(V     + b*TH + i8);
    const u16* n = (const u16*)&pn;
    const u16* v = (const u16*)&pv;
    #pragma unroll
    for (int j = 0; j < 8; ++j){ float nf = bf2f(n[j]); den[j] += nf; ws[j] += nf * bf2f(v[j]); }
  }
  u16 o[8];
  #pragma unroll
  for (int j = 0; j < 8; ++j) o[j] = f2bf(ws[j] * fast_rcp(den[j]));
  *(uint4*)(wgt + i8) = *(const uint4*)o;
}

// ---------------- 128x128 bf16 MFMA GEMM, C = A[M,K] @ Bt[N,K]^T ----------------
// Swapped-operand MFMA: lane holds C[m=...+lr][n=...+quad*4+r] -> packed 8B/16B stores.
// K is a template constant: full K-loop unroll folds all staging/ds addresses into
// base-reg + immediate. LDS frag offsets hoisted (launch_bounds(256,3) for VGPR room).
// AMUL: A-operand = A[m][k] * wgt[m&4095][k] computed during staging (VALU path + ds_write).
// EPI 0: QKV  (out0=sigmoid(+bq), out1=exp(+bk+wbias), out2=+bv), ld=1024
// EPI 1: attn out: x2 = acc + bo + x1   (bf16, ld=512)
// EPI 2: mlp1: h = gelu_tanh(acc + b1)  (bf16, ld=1024)
// EPI 3: mlp2: out = 2*(acc + b2)       (f32,  ld=512)
template<int EPI, int KC, bool AMUL>
__global__ __launch_bounds__(256, 3)
void gemm128(const u16* __restrict__ A, const u16* __restrict__ Bt, int nTiles,
             const float* __restrict__ bias0, const float* __restrict__ wbias,
             u16* __restrict__ out0, u16* __restrict__ out1, u16* __restrict__ out2,
             const float* __restrict__ bias1, const float* __restrict__ bias2,
             const u16* __restrict__ resid, float* __restrict__ outf,
             const u16* __restrict__ wgt){
  __shared__ u16 ldsA[128*64];
  __shared__ u16 ldsB[128*64];
  const int tid  = threadIdx.x;
  const int wid  = tid >> 6;
  const int lane = tid & 63;
  const int quad = lane >> 4;
  const int lr   = lane & 15;

  // swizzled tile decode: groups of 16 M-tiles x all N-tiles, M fastest -> XCD pinning
  const int lin = blockIdx.x;
  const int GS  = 16 * nTiles;
  const int g   = lin / GS;
  const int rem = lin - g * GS;
  const int tileM = (g * 16 + (rem & 15)) * 128;
  const int tileN = (rem >> 4) * 128;

  const int wmBase = (wid & 1) * 64;
  const int wnBase = (wid >> 1) * 64;

  f32x4 acc[4][4] = {};

  // Staging source mapping; XOR swizzle on GLOBAL source, LDS write linear.
  int srow[4], scb[4];
  #pragma unroll
  for (int r = 0; r < 4; ++r){
    const int off = r*4096 + wid*1024 + lane*16;  // byte offset in 16KB tile
    srow[r] = off >> 7;                           // 128B per 64-col bf16 row
    scb[r]  = ((off >> 4) & 7) ^ (srow[r] & 7);
  }
  const u16* aSrc[4]; const u16* bSrc[4];
  const u16* wSrc[4];
  #pragma unroll
  for (int r = 0; r < 4; ++r){
    aSrc[r] = A  + (size_t)(tileM + srow[r]) * KC + scb[r]*8;
    bSrc[r] = Bt + (size_t)(tileN + srow[r]) * KC + scb[r]*8;
    if (AMUL) wSrc[r] = wgt + (size_t)((tileM + srow[r]) & 4095) * KC + scb[r]*8;
  }

  // hoisted LDS fragment byte-offsets (loop-invariant)
  int aOff[2][4], bOff[2][4];
  #pragma unroll
  for (int s = 0; s < 2; ++s)
    #pragma unroll
    for (int i = 0; i < 4; ++i){
      const int m = wmBase + i*16 + lr;
      const int n = wnBase + i*16 + lr;
      aOff[s][i] = m*128 + (((s*4 + quad) ^ (m & 7)) * 16);
      bOff[s][i] = n*128 + (((s*4 + quad) ^ (n & 7)) * 16);
    }

  #pragma unroll
  for (int kt = 0; kt < KC; kt += 64){
    if constexpr (AMUL){
      #pragma unroll
      for (int r = 0; r < 4; ++r){
        uint4 pq = *(const uint4*)(aSrc[r] + kt);
        uint4 pw = *(const uint4*)(wSrc[r] + kt);
        const u16* q = (const u16*)&pq;
        const u16* wv = (const u16*)&pw;
        u16 o[8];
        #pragma unroll
        for (int j = 0; j < 8; ++j) o[j] = f2bf(bf2f(q[j]) * bf2f(wv[j]));
        *(uint4*)((char*)ldsA + r*4096 + wid*1024 + lane*16) = *(const uint4*)o;
      }
    } else {
      #pragma unroll
      for (int r = 0; r < 4; ++r)
        async16(aSrc[r] + kt, (u16*)((char*)ldsA + r*4096 + wid*1024));
    }
    #pragma unroll
    for (int r = 0; r < 4; ++r)
      async16(bSrc[r] + kt, (u16*)((char*)ldsB + r*4096 + wid*1024));
    __syncthreads();
    #pragma unroll
    for (int s = 0; s < 2; ++s){
      bf16x8 ar[4], br[4];
      #pragma unroll
      for (int i = 0; i < 4; ++i) ar[i] = *(const bf16x8*)((const char*)ldsA + aOff[s][i]);
      #pragma unroll
      for (int i = 0; i < 4; ++i) br[i] = *(const bf16x8*)((const char*)ldsB + bOff[s][i]);
      #pragma unroll
      for (int i = 0; i < 4; ++i)
        #pragma unroll
        for (int j = 0; j < 4; ++j)
          acc[i][j] = __builtin_amdgcn_mfma_f32_16x16x32_bf16(br[j], ar[i], acc[i][j], 0, 0, 0);
    }
    __syncthreads();
  }

  // ---- epilogue: lane holds C[row = tileM+wmBase+i*16+lr][col = colb..colb+3] ----
  if (EPI == 0){
    const int mat = tileN >> 10;                  // 0:Q 1:K 2:V (uniform per block)
    const float* biasP = (mat==0) ? bias0 : (mat==1) ? bias1 : bias2;
    u16* outP          = (mat==0) ? out0  : (mat==1) ? out1  : out2;
    const int h0 = (tileN & 1023) + wnBase;
    #pragma unroll
    for (int j = 0; j < 4; ++j){
      const int colb = h0 + j*16 + quad*4;
      const float4 bvv = *(const float4*)(biasP + colb);
      float4 wbv = {0,0,0,0};
      if (mat == 1) wbv = *(const float4*)(wbias + colb);
      #pragma unroll
      for (int i = 0; i < 4; ++i){
        const int row = tileM + wmBase + i*16 + lr;
        u16 o[4];
        #pragma unroll
        for (int r = 0; r < 4; ++r){
          float v = acc[i][j][r] + ((const float*)&bvv)[r];
          if (mat == 0)      v = fast_rcp(1.0f + __expf(-v));
          else if (mat == 1) v = __expf(v + ((const float*)&wbv)[r]);
          o[r] = f2bf(v);
        }
        *(uint2*)(outP + (size_t)row * 1024 + colb) = *(const uint2*)o;
      }
    }
  } else if (EPI == 1){
    #pragma unroll
    for (int j = 0; j < 4; ++j){
      const int colb = tileN + wnBase + j*16 + quad*4;
      const float4 bvv = *(const float4*)(bias0 + colb);
      #pragma unroll
      for (int i = 0; i < 4; ++i){
        const int row = tileM + wmBase + i*16 + lr;
        uint2 pr = *(const uint2*)(resid + (size_t)row * 512 + colb);
        const u16* rp = (const u16*)&pr;
        u16 o[4];
        #pragma unroll
        for (int r = 0; r < 4; ++r)
          o[r] = f2bf(acc[i][j][r] + ((const float*)&bvv)[r] + bf2f(rp[r]));
        *(uint2*)(out0 + (size_t)row * 512 + colb) = *(const uint2*)o;
      }
    }
  } else if (EPI == 2){
    #pragma unroll
    for (int j = 0; j < 4; ++j){
      const int colb = tileN + wnBase + j*16 + quad*4;
      const float4 bvv = *(const float4*)(bias0 + colb);
      #pragma unroll
      for (int i = 0; i < 4; ++i){
        const int row = tileM + wmBase + i*16 + lr;
        u16 o[4];
        #pragma unroll
        for (int r = 0; r < 4; ++r){
          float v = acc[i][j][r] + ((const float*)&bvv)[r];
          float u2 = 2.0f * v * (0.7978845608f + 0.0356774081f * v * v);
          float t  = 1.0f - 2.0f * fast_rcp(1.0f + __expf(u2));
          o[r] = f2bf(0.5f * v * (1.0f + t));
        }
        *(uint2*)(out0 + (size_t)row * 1024 + colb) = *(const uint2*)o;
      }
    }
  } else {
    #pragma unroll
    for (int j = 0; j < 4; ++j){
      const int colb = tileN + wnBase + j*16 + quad*4;
      const float4 bvv = *(const float4*)(bias0 + colb);
      #pragma unroll
      for (int i = 0; i < 4; ++i){
        const int row = tileM + wmBase + i*16 + lr;
        float4 o;
        #pragma unroll
        for (int r = 0; r < 4; ++r)
          ((float*)&o)[r] = 2.0f * (acc[i][j][r] + ((const float*)&bvv)[r]);
        *(float4*)(outf + (size_t)row * 512 + colb) = o;
      }
    }
  }
}

extern "C" void kernel_launch(void* const* d_in, const int* in_sizes, int n_in,
                              void* d_out, int out_size, void* d_ws, size_t ws_size,
                              hipStream_t stream) {
  const float* x     = (const float*)d_in[0];
  const float* gamma = (const float*)d_in[1];
  const float* beta  = (const float*)d_in[2];
  const float* Wq    = (const float*)d_in[3];
  const float* bq    = (const float*)d_in[4];
  const float* Wk    = (const float*)d_in[5];
  const float* bk    = (const float*)d_in[6];
  const float* Wv    = (const float*)d_in[7];
  const float* bv    = (const float*)d_in[8];
  const float* wbias = (const float*)d_in[9];
  const float* Wo    = (const float*)d_in[10];
  const float* bo    = (const float*)d_in[11];
  const float* W1    = (const float*)d_in[12];
  const float* b1    = (const float*)d_in[13];
  const float* W2    = (const float*)d_in[14];
  const float* b2    = (const float*)d_in[15];
  float* out = (float*)d_out;

  char* w = (char*)d_ws;
  const size_t MB = 1ull << 20;
  u16* WqkvT = (u16*)(w + 0*MB);      // [3072][512]  (WqT | WkT | WvT)
  u16* WoT   = (u16*)(w + 3*MB);      // [512][1024]
  u16* W1T   = (u16*)(w + 4*MB);      // [1024][512]
  u16* W2T   = (u16*)(w + 5*MB);      // [512][1024]
  u16* x1b   = (u16*)(w + 6*MB);      // [32768][512]
  u16* Qs    = (u16*)(w + 38*MB);     // [32768][1024]
  u16* Nu    = (u16*)(w + 102*MB);    // [32768][1024]
  u16* Vb    = (u16*)(w + 166*MB);    // [32768][1024]
  u16* Wgt   = (u16*)(w + 230*MB);    // [4096][1024]
  u16* x2b   = Vb;                    // reuse (V consumed by aft_weighted)
  u16* x3b   = (u16*)(w + 198*MB);    // second half of V region
  u16* hb    = Nu;                    // reuse (numer consumed by aft_weighted)

  transpose_all<<<dim3(32, 32, 6), dim3(32, 8), 0, stream>>>(
      Wq, Wk, Wv, Wo, W1, W2,
      WqkvT, WqkvT + 1024*512, WqkvT + 2*1024*512, WoT, W1T, W2T);

  ln_kernel<false><<<8192, 256, 0, stream>>>(x, gamma, beta, x1b);

  gemm128<0, 512, false><<<256*24, 256, 0, stream>>>(x1b, WqkvT, 24,
      bq, wbias, Qs, Nu, Vb, bk, bv, nullptr, nullptr, nullptr);

  aft_weighted<<<2048, 256, 0, stream>>>(Nu, Vb, Wgt);

  // A-operand staged as Qsig * weighted (AMUL) — Yt never materialized
  gemm128<1, 1024, true><<<256*4, 256, 0, stream>>>(Qs, WoT, 4,
      bo, nullptr, x2b, nullptr, nullptr, nullptr, nullptr, x1b, nullptr, Wgt);

  ln_kernel<true><<<8192, 256, 0, stream>>>(x2b, gamma, beta, x3b);

  gemm128<2, 512, false><<<256*8, 256, 0, stream>>>(x3b, W1T, 8,
      b1, nullptr, hb, nullptr, nullptr, nullptr, nullptr, nullptr, nullptr, nullptr);

  gemm128<3, 1024, false><<<256*4, 256, 0, stream>>>(hb, W2T, 4,
      b2, nullptr, nullptr, nullptr, nullptr, nullptr, nullptr, nullptr, out, nullptr);
}

// Round 5
// 472.540 us; speedup vs baseline: 1.0873x; 1.0873x over previous
//
#include <hip/hip_runtime.h>
#include <hip/hip_bf16.h>
#include <cstdint>

using u16 = unsigned short;
using u32 = unsigned int;

typedef __bf16 bf16x8 __attribute__((ext_vector_type(8)));
typedef float  f32x4  __attribute__((ext_vector_type(4)));

#define DEV static __device__ __forceinline__

DEV float bf2f(u16 u){ union { u32 u; float f; } c; c.u = ((u32)u) << 16; return c.f; }

// hardware RNE f32->bf16 (v_cvt_pk_bf16_f32 on gfx950)
DEV u16 f2bf(float f){
  __bf16 h = (__bf16)f;
  return __builtin_bit_cast(u16, h);
}

DEV float fast_rcp(float x){ return __builtin_amdgcn_rcpf(x); }

DEV void async16(const u16* g, u16* l){
  __builtin_amdgcn_global_load_lds((const __attribute__((address_space(1))) u32*)g,
                                   (__attribute__((address_space(3))) u32*)l,
                                   16, 0, 0);
}

// ---------------- fused weight transposes + f32->bf16 (one launch) ----------------
__global__ __launch_bounds__(256)
void transpose_all(const float* __restrict__ W0, const float* __restrict__ W1,
                   const float* __restrict__ W2, const float* __restrict__ W3,
                   const float* __restrict__ W4, const float* __restrict__ W5,
                   u16* __restrict__ T0, u16* __restrict__ T1, u16* __restrict__ T2,
                   u16* __restrict__ T3, u16* __restrict__ T4, u16* __restrict__ T5){
  const int z = blockIdx.z;
  const float* W; u16* WT; int R, C;
  switch (z){
    case 0:  W = W0; WT = T0; R = 512;  C = 1024; break;
    case 1:  W = W1; WT = T1; R = 512;  C = 1024; break;
    case 2:  W = W2; WT = T2; R = 512;  C = 1024; break;
    case 3:  W = W3; WT = T3; R = 1024; C = 512;  break;
    case 4:  W = W4; WT = T4; R = 512;  C = 1024; break;
    default: W = W5; WT = T5; R = 1024; C = 512;  break;
  }
  const int c0 = blockIdx.x * 32, r0 = blockIdx.y * 32;
  if (c0 >= C || r0 >= R) return;
  __shared__ float tile[32][33];
  const int tx = threadIdx.x, ty = threadIdx.y;  // (32,8)
  #pragma unroll
  for (int j = 0; j < 4; ++j)
    tile[ty + j*8][tx] = W[(size_t)(r0 + ty + j*8) * C + (c0 + tx)];
  __syncthreads();
  #pragma unroll
  for (int j = 0; j < 4; ++j)
    WT[(size_t)(c0 + ty + j*8) * R + (r0 + tx)] = f2bf(tile[tx][ty + j*8]);
}

// ---------------- LayerNorm: one wave per 512-elem row ----------------
template<bool BF16IN>
__global__ __launch_bounds__(256)
void ln_kernel(const void* __restrict__ xin, const float* __restrict__ gamma,
               const float* __restrict__ beta, u16* __restrict__ xout){
  const int wid = threadIdx.x >> 6;
  const int lane = threadIdx.x & 63;
  const size_t row = (size_t)blockIdx.x * 4 + wid;
  const int d0 = lane * 8;
  float v[8];
  if constexpr (BF16IN){
    const u16* xp = (const u16*)xin + row * 512 + d0;
    uint4 p = *(const uint4*)xp;
    const u16* s = (const u16*)&p;
    #pragma unroll
    for (int i = 0; i < 8; ++i) v[i] = bf2f(s[i]);
  } else {
    const float* xp = (const float*)xin + row * 512 + d0;
    float4 p0 = *(const float4*)xp;
    float4 p1 = *(const float4*)(xp + 4);
    v[0]=p0.x; v[1]=p0.y; v[2]=p0.z; v[3]=p0.w;
    v[4]=p1.x; v[5]=p1.y; v[6]=p1.z; v[7]=p1.w;
  }
  float s = 0.f, sq = 0.f;
  #pragma unroll
  for (int i = 0; i < 8; ++i){ s += v[i]; sq += v[i]*v[i]; }
  #pragma unroll
  for (int o = 32; o >= 1; o >>= 1){ s += __shfl_xor(s, o); sq += __shfl_xor(sq, o); }
  const float mu  = s * (1.0f/512.0f);
  const float var = sq * (1.0f/512.0f) - mu*mu;
  const float rstd = rsqrtf(var + 1e-5f);
  const float4 g0 = *(const float4*)(gamma + d0);
  const float4 g1 = *(const float4*)(gamma + d0 + 4);
  const float4 b0 = *(const float4*)(beta + d0);
  const float4 b1 = *(const float4*)(beta + d0 + 4);
  const float* gp = (const float*)&g0;  // g0,g1 contiguous on stack? keep simple:
  float gg[8] = {g0.x,g0.y,g0.z,g0.w,g1.x,g1.y,g1.z,g1.w};
  float bb[8] = {b0.x,b0.y,b0.z,b0.w,b1.x,b1.y,b1.z,b1.w};
  (void)gp;
  u16 o8[8];
  #pragma unroll
  for (int i = 0; i < 8; ++i)
    o8[i] = f2bf((v[i]-mu)*rstd*gg[i] + bb[i]);
  *(uint4*)(xout + row*512 + d0) = *(const uint4*)o8;
}

// ---- fused AFT: weighted[t,h] = sum_b n*v / sum_b n ; Yt[b,t,h] = Qsig[b,t,h]*weighted ----
// Yt written in-place over numer (same thread reads numer[b,i8] before writing Yt[b,i8]).
__global__ __launch_bounds__(256)
void aft_fused(const u16* __restrict__ numer, const u16* __restrict__ V,
               const u16* __restrict__ qs, u16* __restrict__ yt){
  const size_t TH = (size_t)4096 * 1024;
  const size_t i8 = ((size_t)blockIdx.x * 256 + threadIdx.x) * 8;
  float den[8], ws[8];
  #pragma unroll
  for (int j = 0; j < 8; ++j){ den[j] = 0.f; ws[j] = 0.f; }
  #pragma unroll
  for (int b = 0; b < 8; ++b){
    uint4 pn = *(const uint4*)(numer + b*TH + i8);
    uint4 pv = *(const uint4*)(V     + b*TH + i8);
    const u16* n = (const u16*)&pn;
    const u16* v = (const u16*)&pv;
    #pragma unroll
    for (int j = 0; j < 8; ++j){ float nf = bf2f(n[j]); den[j] += nf; ws[j] += nf * bf2f(v[j]); }
  }
  float w[8];
  #pragma unroll
  for (int j = 0; j < 8; ++j) w[j] = ws[j] * fast_rcp(den[j]);
  #pragma unroll
  for (int b = 0; b < 8; ++b){
    uint4 pq = *(const uint4*)(qs + b*TH + i8);
    const u16* q = (const u16*)&pq;
    u16 o[8];
    #pragma unroll
    for (int j = 0; j < 8; ++j) o[j] = f2bf(bf2f(q[j]) * w[j]);
    *(uint4*)(yt + b*TH + i8) = *(const uint4*)o;
  }
}

// ---------------- 128x128 bf16 MFMA GEMM, C = A[M,K] @ Bt[N,K]^T ----------------
// Swapped-operand MFMA: lane holds C[m=...+lr][n=...+quad*4+r].
// Templated K: full unroll, all addresses base+immediate; LDS frag offsets hoisted.
// Epilogue (bf16 outs): per-wave LDS bounce (row stride 144B) -> full 128-B-line
// global stores (2x dwordx4/lane), immune to L2 partial-sector writeback.
// EPI 0: QKV  (out0=sigmoid(+bq), out1=exp(+bk+wbias), out2=+bv), ld=1024
// EPI 1: attn out: x2 = acc + bo + x1   (bf16, ld=512)
// EPI 2: mlp1: h = gelu_tanh(acc + b1)  (bf16, ld=1024)
// EPI 3: mlp2: out = 2*(acc + b2)       (f32,  ld=512, direct 16B stores)
template<int EPI, int KC>
__global__ __launch_bounds__(256, 3)
void gemm128(const u16* __restrict__ A, const u16* __restrict__ Bt, int nTiles,
             const float* __restrict__ bias0, const float* __restrict__ wbias,
             u16* __restrict__ out0, u16* __restrict__ out1, u16* __restrict__ out2,
             const float* __restrict__ bias1, const float* __restrict__ bias2,
             const u16* __restrict__ resid, float* __restrict__ outf){
  __shared__ u16 ldsA[128*64];
  __shared__ u16 ldsB[128*64];
  const int tid  = threadIdx.x;
  const int wid  = tid >> 6;
  const int lane = tid & 63;
  const int quad = lane >> 4;
  const int lr   = lane & 15;

  // swizzled tile decode: groups of 16 M-tiles x all N-tiles, M fastest -> XCD pinning
  const int lin = blockIdx.x;
  const int GS  = 16 * nTiles;
  const int g   = lin / GS;
  const int rem = lin - g * GS;
  const int tileM = (g * 16 + (rem & 15)) * 128;
  const int tileN = (rem >> 4) * 128;

  const int wmBase = (wid & 1) * 64;
  const int wnBase = (wid >> 1) * 64;

  f32x4 acc[4][4] = {};

  // Staging source mapping; XOR swizzle on GLOBAL source, LDS write linear.
  int srow[4], scb[4];
  #pragma unroll
  for (int r = 0; r < 4; ++r){
    const int off = r*4096 + wid*1024 + lane*16;  // byte offset in 16KB tile
    srow[r] = off >> 7;                           // 128B per 64-col bf16 row
    scb[r]  = ((off >> 4) & 7) ^ (srow[r] & 7);
  }
  const u16* aSrc[4]; const u16* bSrc[4];
  #pragma unroll
  for (int r = 0; r < 4; ++r){
    aSrc[r] = A  + (size_t)(tileM + srow[r]) * KC + scb[r]*8;
    bSrc[r] = Bt + (size_t)(tileN + srow[r]) * KC + scb[r]*8;
  }

  // hoisted LDS fragment byte-offsets (loop-invariant)
  int aOff[2][4], bOff[2][4];
  #pragma unroll
  for (int s = 0; s < 2; ++s)
    #pragma unroll
    for (int i = 0; i < 4; ++i){
      const int m = wmBase + i*16 + lr;
      const int n = wnBase + i*16 + lr;
      aOff[s][i] = m*128 + (((s*4 + quad) ^ (m & 7)) * 16);
      bOff[s][i] = n*128 + (((s*4 + quad) ^ (n & 7)) * 16);
    }

  #pragma unroll
  for (int kt = 0; kt < KC; kt += 64){
    #pragma unroll
    for (int r = 0; r < 4; ++r){
      async16(aSrc[r] + kt, (u16*)((char*)ldsA + r*4096 + wid*1024));
      async16(bSrc[r] + kt, (u16*)((char*)ldsB + r*4096 + wid*1024));
    }
    __syncthreads();
    #pragma unroll
    for (int s = 0; s < 2; ++s){
      bf16x8 ar[4], br[4];
      #pragma unroll
      for (int i = 0; i < 4; ++i) ar[i] = *(const bf16x8*)((const char*)ldsA + aOff[s][i]);
      #pragma unroll
      for (int i = 0; i < 4; ++i) br[i] = *(const bf16x8*)((const char*)ldsB + bOff[s][i]);
      #pragma unroll
      for (int i = 0; i < 4; ++i)
        #pragma unroll
        for (int j = 0; j < 4; ++j)
          acc[i][j] = __builtin_amdgcn_mfma_f32_16x16x32_bf16(br[j], ar[i], acc[i][j], 0, 0, 0);
    }
    __syncthreads();
  }

  // ---- epilogue ----
  // lane holds C[row = tileM+wmBase+i*16+lr][col = cb0 + j*16+quad*4 .. +3]
  if (EPI == 3){
    #pragma unroll
    for (int j = 0; j < 4; ++j){
      const int colb = tileN + wnBase + j*16 + quad*4;
      const float4 bvv = *(const float4*)(bias0 + colb);
      #pragma unroll
      for (int i = 0; i < 4; ++i){
        const int row = tileM + wmBase + i*16 + lr;
        float4 o;
        #pragma unroll
        for (int r = 0; r < 4; ++r)
          ((float*)&o)[r] = 2.0f * (acc[i][j][r] + ((const float*)&bvv)[r]);
        *(float4*)(outf + (size_t)row * 512 + colb) = o;
      }
    }
    return;
  }

  // bf16 epilogues with LDS bounce. After final barrier ldsA is reusable;
  // each wave touches only its own 2304-B region.
  u16* eb = ldsA + wid * 1152;          // u16 units; row stride 72 u16 (144 B)
  const int mat = (EPI == 0) ? (tileN >> 10) : 0;   // 0:Q 1:K 2:V
  const float* biasP = bias0;
  u16* outP = out0;
  int ldO = 1024, cb0 = tileN + wnBase;
  if (EPI == 0){
    biasP = (mat==0) ? bias0 : (mat==1) ? bias1 : bias2;
    outP  = (mat==0) ? out0  : (mat==1) ? out1  : out2;
    cb0   = (tileN & 1023) + wnBase;
  } else if (EPI == 1){
    ldO = 512;
  }

  #pragma unroll
  for (int i = 0; i < 4; ++i){
    const int row = tileM + wmBase + i*16 + lr;
    #pragma unroll
    for (int j = 0; j < 4; ++j){
      const int cl = j*16 + quad*4;
      const float4 bvv = *(const float4*)(biasP + cb0 + cl);
      u16 o[4];
      if (EPI == 0){
        float4 wbv = {0,0,0,0};
        if (mat == 1) wbv = *(const float4*)(wbias + cb0 + cl);
        #pragma unroll
        for (int r = 0; r < 4; ++r){
          float v = acc[i][j][r] + ((const float*)&bvv)[r];
          if (mat == 0)      v = fast_rcp(1.0f + __expf(-v));
          else if (mat == 1) v = __expf(v + ((const float*)&wbv)[r]);
          o[r] = f2bf(v);
        }
      } else if (EPI == 1){
        uint2 pr = *(const uint2*)(resid + (size_t)row * 512 + cb0 + cl);
        const u16* rp = (const u16*)&pr;
        #pragma unroll
        for (int r = 0; r < 4; ++r)
          o[r] = f2bf(acc[i][j][r] + ((const float*)&bvv)[r] + bf2f(rp[r]));
      } else {
        #pragma unroll
        for (int r = 0; r < 4; ++r){
          float v = acc[i][j][r] + ((const float*)&bvv)[r];
          float u2 = 2.0f * v * (0.7978845608f + 0.0356774081f * v * v);
          float t  = 1.0f - 2.0f * fast_rcp(1.0f + __expf(u2));
          o[r] = f2bf(0.5f * v * (1.0f + t));
        }
      }
      *(uint2*)(eb + lr*72 + cl) = *(const uint2*)o;
    }
    __asm__ volatile("s_waitcnt lgkmcnt(0)" ::: "memory");
    uint4 p0 = *(const uint4*)(eb + lr*72 + quad*16);
    uint4 p1 = *(const uint4*)(eb + lr*72 + quad*16 + 8);
    __asm__ volatile("s_waitcnt lgkmcnt(0)" ::: "memory");
    u16* gp = outP + (size_t)row * ldO + cb0 + quad*16;
    *(uint4*)gp = p0;
    *(uint4*)(gp + 8) = p1;
  }
}

extern "C" void kernel_launch(void* const* d_in, const int* in_sizes, int n_in,
                              void* d_out, int out_size, void* d_ws, size_t ws_size,
                              hipStream_t stream) {
  const float* x     = (const float*)d_in[0];
  const float* gamma = (const float*)d_in[1];
  const float* beta  = (const float*)d_in[2];
  const float* Wq    = (const float*)d_in[3];
  const float* bq    = (const float*)d_in[4];
  const float* Wk    = (const float*)d_in[5];
  const float* bk    = (const float*)d_in[6];
  const float* Wv    = (const float*)d_in[7];
  const float* bv    = (const float*)d_in[8];
  const float* wbias = (const float*)d_in[9];
  const float* Wo    = (const float*)d_in[10];
  const float* bo    = (const float*)d_in[11];
  const float* W1    = (const float*)d_in[12];
  const float* b1    = (const float*)d_in[13];
  const float* W2    = (const float*)d_in[14];
  const float* b2    = (const float*)d_in[15];
  float* out = (float*)d_out;

  char* w = (char*)d_ws;
  const size_t MB = 1ull << 20;
  u16* WqkvT = (u16*)(w + 0*MB);      // [3072][512]  (WqT | WkT | WvT)
  u16* WoT   = (u16*)(w + 3*MB);      // [512][1024]
  u16* W1T   = (u16*)(w + 4*MB);      // [1024][512]
  u16* W2T   = (u16*)(w + 5*MB);      // [512][1024]
  u16* x1b   = (u16*)(w + 6*MB);      // [32768][512]
  u16* Qs    = (u16*)(w + 38*MB);     // [32768][1024]
  u16* Nu    = (u16*)(w + 102*MB);    // [32768][1024]
  u16* Vb    = (u16*)(w + 166*MB);    // [32768][1024]
  u16* Yt    = Nu;                    // in-place over numer (per-thread RAW order)
  u16* x2b   = Vb;                    // reuse (V consumed by aft_fused)
  u16* x3b   = (u16*)(w + 198*MB);    // second half of V region
  u16* hb    = Qs;                    // reuse (Qsig consumed by aft_fused)

  transpose_all<<<dim3(32, 32, 6), dim3(32, 8), 0, stream>>>(
      Wq, Wk, Wv, Wo, W1, W2,
      WqkvT, WqkvT + 1024*512, WqkvT + 2*1024*512, WoT, W1T, W2T);

  ln_kernel<false><<<8192, 256, 0, stream>>>(x, gamma, beta, x1b);

  gemm128<0, 512><<<256*24, 256, 0, stream>>>(x1b, WqkvT, 24,
      bq, wbias, Qs, Nu, Vb, bk, bv, nullptr, nullptr);

  aft_fused<<<2048, 256, 0, stream>>>(Nu, Vb, Qs, Yt);

  gemm128<1, 1024><<<256*4, 256, 0, stream>>>(Yt, WoT, 4,
      bo, nullptr, x2b, nullptr, nullptr, nullptr, nullptr, x1b, nullptr);

  ln_kernel<true><<<8192, 256, 0, stream>>>(x2b, gamma, beta, x3b);

  gemm128<2, 512><<<256*8, 256, 0, stream>>>(x3b, W1T, 8,
      b1, nullptr, hb, nullptr, nullptr, nullptr, nullptr, nullptr, nullptr);

  gemm128<3, 1024><<<256*4, 256, 0, stream>>>(hb, W2T, 4,
      b2, nullptr, nullptr, nullptr, nullptr, nullptr, nullptr, nullptr, out);
}